// Round 1
// 498.887 us; speedup vs baseline: 1.0160x; 1.0160x over previous
//
#include <hip/hip_runtime.h>

typedef __attribute__((ext_vector_type(8))) short short8;
typedef __attribute__((ext_vector_type(4))) float floatx4;

// ---- bf16 split helpers (round-to-nearest-even) ----
static __device__ __forceinline__ unsigned short f2bf(float f) {
    unsigned u = __float_as_uint(f);
    u += 0x7fff + ((u >> 16) & 1);
    return (unsigned short)(u >> 16);
}
static __device__ __forceinline__ float bf2f(unsigned short h) {
    return __uint_as_float((unsigned)h << 16);
}
static __device__ __forceinline__ unsigned packsplit(float f) {
    unsigned short hi = f2bf(f);
    unsigned short lo = f2bf(f - bf2f(hi));
    return ((unsigned)hi << 16) | lo;
}

// ---------------- CSR build (degi memset to 0 by host-side hipMemsetAsync) ----------------
// NOTE: CSR now contains ONLY the E real edges; self-loops are streamed in agg_kernel.

__global__ void count_kernel(const int* __restrict__ ei, int* degi, int E) {
    int e = blockIdx.x * 256 + threadIdx.x;
    if (e < E) atomicAdd(&degi[ei[E + e]], 1);   // col = dest
}

// per-block sums of 256 deg values (real edges only), + fused dinv (deg+1 incl self-loop)
__global__ __launch_bounds__(256) void scan_bsum_kernel(const int* __restrict__ degi,
                                                        float* __restrict__ dinv,
                                                        int* bsum, int n) {
    int tid = threadIdx.x;
    int i = blockIdx.x * 256 + tid;
    int d = (i < n) ? degi[i] : 0;
    if (i < n) dinv[i] = rsqrtf((float)(d + 1));  // +1 self-loop for normalization
    int v = d;                                    // offsets count only real edges
    #pragma unroll
    for (int off = 32; off > 0; off >>= 1) v += __shfl_down(v, off);
    __shared__ int ws[4];
    if ((tid & 63) == 0) ws[tid >> 6] = v;
    __syncthreads();
    if (tid == 0) bsum[blockIdx.x] = ws[0] + ws[1] + ws[2] + ws[3];
}

// emit rp/cursor; fused block-offset reduction (no separate scan_sums kernel)
__global__ __launch_bounds__(256) void scan_emit_kernel(const int* __restrict__ degi,
                                                        const int* __restrict__ bsum,
                                                        int* rp, int* cursor, int n, int nb) {
    int tid = threadIdx.x;
    int bid = blockIdx.x;
    // boff = sum of bsum[0..bid)
    int contrib = 0;
    for (int t = tid; t < bid; t += 256) contrib += bsum[t];
    int cr = contrib;
    #pragma unroll
    for (int off = 32; off > 0; off >>= 1) cr += __shfl_down(cr, off);
    __shared__ int wr[4];
    __shared__ int s_boff;
    if ((tid & 63) == 0) wr[tid >> 6] = cr;
    __syncthreads();
    if (tid == 0) s_boff = wr[0] + wr[1] + wr[2] + wr[3];
    __syncthreads();

    int i = bid * 256 + tid;
    int v = (i < n) ? degi[i] : 0;                // real edges only
    int lane = tid & 63, wid = tid >> 6;
    int x = v;
    #pragma unroll
    for (int off = 1; off < 64; off <<= 1) {
        int y = __shfl_up(x, off);
        if (lane >= off) x += y;
    }
    __shared__ int ws[4];
    if (lane == 63) ws[wid] = x;
    __syncthreads();
    if (tid == 0) { int a = 0; for (int j = 0; j < 4; ++j) { int t = ws[j]; ws[j] = a; a += t; } }
    __syncthreads();
    int excl = x - v + ws[wid] + s_boff;
    if (i < n) { rp[i] = excl; cursor[i] = excl; }
    if (i == n - 1) rp[n] = excl + v;
}

__global__ void fill_kernel(const int* __restrict__ ei, const float* __restrict__ dinv,
                            int* cursor, long long* __restrict__ csr, int E) {
    int e = blockIdx.x * 256 + threadIdx.x;
    if (e >= E) return;
    int r = ei[e], c = ei[E + e];
    int pos = atomicAdd(&cursor[c], 1);
    float wv = dinv[r] * dinv[c];
    long long packed = (long long)(unsigned int)r
                     | ((long long)(unsigned int)__float_as_int(wv) << 32);
    csr[pos] = packed;
}

// ---------------- weight packing: W[k][n] -> Wt_hi[n][k], Wt_lo[n][k] ----------------

__global__ void packw_kernel(const float* w0, const float* w1, const float* w2,
                             const float* w3, const float* w4, const float* w5,
                             unsigned short* __restrict__ hi, unsigned short* __restrict__ lo) {
    int l = blockIdx.y;
    const float* W = (l == 0) ? w0 : (l == 1) ? w1 : (l == 2) ? w2
                   : (l == 3) ? w3 : (l == 4) ? w4 : w5;
    int idx = blockIdx.x * 256 + threadIdx.x;
    int k = idx >> 7, nn = idx & 127;
    float v = W[k * 128 + nn];
    unsigned short h = f2bf(v);
    unsigned short ls = f2bf(v - bf2f(h));
    hi[l * 16384 + nn * 128 + k] = h;
    lo[l * 16384 + nn * 128 + k] = ls;
}

// ---------------- split-bf16 MFMA GEMM core ----------------
// Wt_hi/Wt_lo staged into LDS (stride 260 shorts: hi[0..127], lo[128..255] per row).
// 512 threads = 8 waves x 16 rows = 128 rows/block.
// Fragments (verified R5): a[j]=A[m=lane&15][k=quad*8+j], D: col=lane&15, row=quad*4+reg.

#define WLDS_STRIDE 260

static __device__ __forceinline__ void stage_w(const unsigned short* __restrict__ Wth,
                                               const unsigned short* __restrict__ Wtl,
                                               unsigned short* Wlds, int tid) {
    #pragma unroll
    for (int it = 0; it < 8; ++it) {
        int c = it * 512 + tid;
        int row = c >> 5, piece = c & 31;
        const unsigned short* src = (piece < 16)
            ? (Wth + (size_t)row * 128 + piece * 8)
            : (Wtl + (size_t)row * 128 + (piece - 16) * 8);
        int dst = row * WLDS_STRIDE + ((piece < 16) ? piece * 8 : 128 + (piece - 16) * 8);
        *(short8*)&Wlds[dst] = *(const short8*)src;
    }
}

static __device__ __forceinline__ void unpack_u(uint4 u0, uint4 u1, short8& ah, short8& al) {
    ah[0] = (short)(u0.x >> 16); al[0] = (short)(u0.x & 0xffff);
    ah[1] = (short)(u0.y >> 16); al[1] = (short)(u0.y & 0xffff);
    ah[2] = (short)(u0.z >> 16); al[2] = (short)(u0.z & 0xffff);
    ah[3] = (short)(u0.w >> 16); al[3] = (short)(u0.w & 0xffff);
    ah[4] = (short)(u1.x >> 16); al[4] = (short)(u1.x & 0xffff);
    ah[5] = (short)(u1.y >> 16); al[5] = (short)(u1.y & 0xffff);
    ah[6] = (short)(u1.z >> 16); al[6] = (short)(u1.z & 0xffff);
    ah[7] = (short)(u1.w >> 16); al[7] = (short)(u1.w & 0xffff);
}

__global__ __launch_bounds__(512) void gemm_kernel(const unsigned* __restrict__ Ap,
                                                   const unsigned short* __restrict__ Wth,
                                                   const unsigned short* __restrict__ Wtl,
                                                   float* __restrict__ C, int n) {
    __shared__ unsigned short Wlds[128 * WLDS_STRIDE];
    int tid = threadIdx.x;
    int wave = tid >> 6, lane = tid & 63;
    int m = lane & 15, quad = lane >> 4;
    int row0 = blockIdx.x * 128 + wave * 16;
    int arow = row0 + m; if (arow > n - 1) arow = n - 1;
    const unsigned* aptr = Ap + (size_t)arow * 128 + quad * 8;

    // prefetch kc=0 A before staging W (overlap global latency with LDS fill)
    uint4 p0 = *(const uint4*)(aptr);
    uint4 p1 = *(const uint4*)(aptr + 4);

    stage_w(Wth, Wtl, Wlds, tid);

    floatx4 acc[8];
    #pragma unroll
    for (int ct = 0; ct < 8; ++ct) acc[ct] = (floatx4){0.f, 0.f, 0.f, 0.f};
    __syncthreads();

    #pragma unroll
    for (int kc = 0; kc < 4; ++kc) {
        uint4 u0, u1;
        if (kc == 0) { u0 = p0; u1 = p1; }
        else { u0 = *(const uint4*)(aptr + kc * 32); u1 = *(const uint4*)(aptr + kc * 32 + 4); }
        short8 ah, al;
        unpack_u(u0, u1, ah, al);
        #pragma unroll
        for (int ct = 0; ct < 8; ++ct) {
            int base = (ct * 16 + m) * WLDS_STRIDE + kc * 32 + quad * 8;
            short8 wh = *(const short8*)&Wlds[base];
            short8 wl = *(const short8*)&Wlds[base + 128];
            acc[ct] = __builtin_amdgcn_mfma_f32_16x16x32_bf16(al, wl, acc[ct], 0, 0, 0);
            acc[ct] = __builtin_amdgcn_mfma_f32_16x16x32_bf16(ah, wl, acc[ct], 0, 0, 0);
            acc[ct] = __builtin_amdgcn_mfma_f32_16x16x32_bf16(al, wh, acc[ct], 0, 0, 0);
            acc[ct] = __builtin_amdgcn_mfma_f32_16x16x32_bf16(ah, wh, acc[ct], 0, 0, 0);
        }
    }
    #pragma unroll
    for (int ct = 0; ct < 8; ++ct) {
        #pragma unroll
        for (int r = 0; r < 4; ++r) {
            int row = row0 + quad * 4 + r;
            if (row < n) C[(size_t)row * 128 + ct * 16 + m] = acc[ct][r];
        }
    }
}

// layer-0 variant: reads fp32 x directly, splits inline (packx kernel eliminated)
__global__ __launch_bounds__(512) void gemm0_kernel(const float* __restrict__ X,
                                                    const unsigned short* __restrict__ Wth,
                                                    const unsigned short* __restrict__ Wtl,
                                                    float* __restrict__ C, int n) {
    __shared__ unsigned short Wlds[128 * WLDS_STRIDE];
    int tid = threadIdx.x;
    int wave = tid >> 6, lane = tid & 63;
    int m = lane & 15, quad = lane >> 4;
    int row0 = blockIdx.x * 128 + wave * 16;
    int arow = row0 + m; if (arow > n - 1) arow = n - 1;
    const float* aptr = X + (size_t)arow * 128 + quad * 8;

    float4 pf0 = *(const float4*)(aptr);
    float4 pf1 = *(const float4*)(aptr + 4);

    stage_w(Wth, Wtl, Wlds, tid);

    floatx4 acc[8];
    #pragma unroll
    for (int ct = 0; ct < 8; ++ct) acc[ct] = (floatx4){0.f, 0.f, 0.f, 0.f};
    __syncthreads();

    #pragma unroll
    for (int kc = 0; kc < 4; ++kc) {
        float4 f0, f1;
        if (kc == 0) { f0 = pf0; f1 = pf1; }
        else { f0 = *(const float4*)(aptr + kc * 32); f1 = *(const float4*)(aptr + kc * 32 + 4); }
        float fv[8] = {f0.x, f0.y, f0.z, f0.w, f1.x, f1.y, f1.z, f1.w};
        short8 ah, al;
        #pragma unroll
        for (int j = 0; j < 8; ++j) {
            unsigned short h = f2bf(fv[j]);
            ah[j] = (short)h;
            al[j] = (short)f2bf(fv[j] - bf2f(h));
        }
        #pragma unroll
        for (int ct = 0; ct < 8; ++ct) {
            int base = (ct * 16 + m) * WLDS_STRIDE + kc * 32 + quad * 8;
            short8 wh = *(const short8*)&Wlds[base];
            short8 wl = *(const short8*)&Wlds[base + 128];
            acc[ct] = __builtin_amdgcn_mfma_f32_16x16x32_bf16(al, wl, acc[ct], 0, 0, 0);
            acc[ct] = __builtin_amdgcn_mfma_f32_16x16x32_bf16(ah, wl, acc[ct], 0, 0, 0);
            acc[ct] = __builtin_amdgcn_mfma_f32_16x16x32_bf16(al, wh, acc[ct], 0, 0, 0);
            acc[ct] = __builtin_amdgcn_mfma_f32_16x16x32_bf16(ah, wh, acc[ct], 0, 0, 0);
        }
    }
    #pragma unroll
    for (int ct = 0; ct < 8; ++ct) {
        #pragma unroll
        for (int r = 0; r < 4; ++r) {
            int row = row0 + quad * 4 + r;
            if (row < n) C[(size_t)row * 128 + ct * 16 + m] = acc[ct][r];
        }
    }
}

// ---------------- aggregation ----------------
// One node per 32-lane group (lane handles 4 of 128 cols).
// Self-loop streamed (coalesced) before the loop; edge loop is masked unroll-8:
// always 8 csr loads + 8 gathers in flight (tail slots clamp the index to p1-1,
// always in-bounds since loop only entered when p < p1, and weight forced to 0).
// This removes the serial 1-wide remainder loop and roughly halves the number of
// dependent memory round-trips per node (~5 -> ~2).

__global__ __launch_bounds__(256) void agg_kernel(const float* __restrict__ t,
                                                  const float* __restrict__ bias,
                                                  const int* __restrict__ rp,
                                                  const long long* __restrict__ csr,
                                                  const float* __restrict__ dinv,
                                                  unsigned* __restrict__ hp, int n) {
    int local = threadIdx.x & 31;
    int j = blockIdx.x * 8 + (threadIdx.x >> 5);
    if (j >= n) return;
    int c4 = local * 4;
    int p0 = rp[j], p1 = rp[j + 1];

    // self-loop term: coalesced sequential read, issued first (overlaps csr latency)
    float dj = dinv[j];
    float ws = dj * dj;
    float4 vs = *(const float4*)&t[(size_t)j * 128 + c4];

    float4 acc[4];
    acc[0] = make_float4(ws * vs.x, ws * vs.y, ws * vs.z, ws * vs.w);
    acc[1] = make_float4(0.f, 0.f, 0.f, 0.f);
    acc[2] = make_float4(0.f, 0.f, 0.f, 0.f);
    acc[3] = make_float4(0.f, 0.f, 0.f, 0.f);

    for (int p = p0; p < p1; p += 8) {
        int lim = p1 - 1;
        long long e[8];
        #pragma unroll
        for (int i = 0; i < 8; ++i) e[i] = csr[min(p + i, lim)];
        float w[8];
        #pragma unroll
        for (int i = 0; i < 8; ++i)
            w[i] = (p + i < p1) ? __int_as_float((int)(e[i] >> 32)) : 0.f;
        float4 v[8];
        #pragma unroll
        for (int i = 0; i < 8; ++i)
            v[i] = *(const float4*)&t[(size_t)(int)e[i] * 128 + c4];
        #pragma unroll
        for (int i = 0; i < 8; ++i) {
            acc[i & 3].x += w[i] * v[i].x;
            acc[i & 3].y += w[i] * v[i].y;
            acc[i & 3].z += w[i] * v[i].z;
            acc[i & 3].w += w[i] * v[i].w;
        }
    }

    float4 b = *(const float4*)&bias[c4];
    float ox = fmaxf(acc[0].x + acc[1].x + acc[2].x + acc[3].x + b.x, 0.f);
    float oy = fmaxf(acc[0].y + acc[1].y + acc[2].y + acc[3].y + b.y, 0.f);
    float oz = fmaxf(acc[0].z + acc[1].z + acc[2].z + acc[3].z + b.z, 0.f);
    float ow = fmaxf(acc[0].w + acc[1].w + acc[2].w + acc[3].w + b.w, 0.f);
    uint4 st;
    st.x = packsplit(ox); st.y = packsplit(oy); st.z = packsplit(oz); st.w = packsplit(ow);
    *(uint4*)&hp[(size_t)j * 128 + c4] = st;
}

// ---------------- pooling + classifier (one block per graph, no atomics) ----------------

__global__ __launch_bounds__(256) void pool_kernel(const float* __restrict__ t,
                                                   const float* __restrict__ bfc,
                                                   const int* __restrict__ batch,
                                                   const float* __restrict__ Wlin,
                                                   const float* __restrict__ blin,
                                                   float* __restrict__ out, int n) {
    int g = blockIdx.x;
    int tid = threadIdx.x;
    int lo = 0, hi = n;
    while (lo < hi) { int m = (lo + hi) >> 1; if (batch[m] < g) lo = m + 1; else hi = m; }
    int start = lo;
    lo = start; hi = n;
    while (lo < hi) { int m = (lo + hi) >> 1; if (batch[m] < g + 1) lo = m + 1; else hi = m; }
    int end = lo;

    int lane = tid & 31, sub = tid >> 5;
    int c4 = lane * 4;
    float4 bv = *(const float4*)&bfc[c4];
    float sx = 0.f, sy = 0.f, sz = 0.f, sw = 0.f;
    for (int j = start + sub; j < end; j += 8) {
        float4 v = *(const float4*)&t[(size_t)j * 128 + c4];
        sx += fmaxf(v.x + bv.x, 0.f);
        sy += fmaxf(v.y + bv.y, 0.f);
        sz += fmaxf(v.z + bv.z, 0.f);
        sw += fmaxf(v.w + bv.w, 0.f);
    }
    __shared__ float red[8][128];
    red[sub][c4] = sx; red[sub][c4 + 1] = sy; red[sub][c4 + 2] = sz; red[sub][c4 + 3] = sw;
    __syncthreads();
    __shared__ float pooled[128];
    if (tid < 128) {
        float s = 0.f;
        #pragma unroll
        for (int k = 0; k < 8; ++k) s += red[k][tid];
        float pv = s / fmaxf((float)(end - start), 1.f);
        pooled[tid] = pv;
        out[1280 + g * 128 + tid] = pv;
    }
    __syncthreads();
    if (tid < 10) {
        float a = blin[tid];
        for (int k = 0; k < 128; ++k) a += pooled[k] * Wlin[k * 10 + tid];
        out[g * 10 + tid] = a;
    }
}

// ---------------- launch ----------------

extern "C" void kernel_launch(void* const* d_in, const int* in_sizes, int n_in,
                              void* d_out, int out_size, void* d_ws, size_t ws_size,
                              hipStream_t stream) {
    const float* x     = (const float*)d_in[0];
    const int*   ei    = (const int*)d_in[1];
    const int*   batch = (const int*)d_in[2];
    const float* Wl[6] = {(const float*)d_in[3], (const float*)d_in[5], (const float*)d_in[7],
                          (const float*)d_in[9], (const float*)d_in[11], (const float*)d_in[13]};
    const float* bl[6] = {(const float*)d_in[4], (const float*)d_in[6], (const float*)d_in[8],
                          (const float*)d_in[10], (const float*)d_in[12], (const float*)d_in[14]};
    const float* Wlin = (const float*)d_in[15];
    const float* blin = (const float*)d_in[16];

    const int N = in_sizes[2];        // 50000
    const int E = in_sizes[1] / 2;    // 600000
    (void)n_in; (void)out_size; (void)ws_size;

    char* p = (char*)d_ws;
    auto carve = [&](size_t bytes) { void* r = (void*)p; p += (bytes + 255) & ~(size_t)255; return r; };
    float*          t      = (float*)carve((size_t)N * 128 * 4);      // fp32 gemm output
    unsigned*       hp     = (unsigned*)carve((size_t)N * 128 * 4);   // packed agg output
    int*            degi   = (int*)carve((size_t)N * 4);
    float*          dinv   = (float*)carve((size_t)N * 4);
    int*            rp     = (int*)carve((size_t)(N + 1) * 4);
    int*            cursor = (int*)carve((size_t)N * 4);
    long long*      csr    = (long long*)carve((size_t)(E + N) * 8);
    int*            bsum   = (int*)carve(256 * 4);
    unsigned short* wth    = (unsigned short*)carve(6 * 16384 * 2);
    unsigned short* wtl    = (unsigned short*)carve(6 * 16384 * 2);

    int gN = (N + 255) / 256;
    hipMemsetAsync(degi, 0, (size_t)N * 4, stream);
    count_kernel<<<(E + 255) / 256, 256, 0, stream>>>(ei, degi, E);
    scan_bsum_kernel<<<gN, 256, 0, stream>>>(degi, dinv, bsum, N);
    scan_emit_kernel<<<gN, 256, 0, stream>>>(degi, bsum, rp, cursor, N, gN);
    fill_kernel<<<(E + 255) / 256, 256, 0, stream>>>(ei, dinv, cursor, csr, E);
    packw_kernel<<<dim3(64, 6), 256, 0, stream>>>(Wl[0], Wl[1], Wl[2], Wl[3], Wl[4], Wl[5],
                                                  wth, wtl);

    int gGemm = (N + 127) / 128;
    int gAgg  = (N + 7) / 8;
    gemm0_kernel<<<gGemm, 512, 0, stream>>>(x, wth, wtl, t, N);
    agg_kernel<<<gAgg, 256, 0, stream>>>(t, bl[0], rp, csr, dinv, hp, N);
    for (int l = 1; l < 5; ++l) {
        gemm_kernel<<<gGemm, 512, 0, stream>>>(hp, wth + l * 16384, wtl + l * 16384, t, N);
        agg_kernel<<<gAgg, 256, 0, stream>>>(t, bl[l], rp, csr, dinv, hp, N);
    }
    gemm_kernel<<<gGemm, 512, 0, stream>>>(hp, wth + 5 * 16384, wtl + 5 * 16384, t, N);
    pool_kernel<<<128, 256, 0, stream>>>(t, bl[5], batch, Wlin, blin, (float*)d_out, N);
}

// Round 2
// 493.585 us; speedup vs baseline: 1.0269x; 1.0107x over previous
//
#include <hip/hip_runtime.h>

typedef __attribute__((ext_vector_type(8))) short short8;
typedef __attribute__((ext_vector_type(4))) float floatx4;

// ---- bf16 split helpers (round-to-nearest-even) ----
static __device__ __forceinline__ unsigned short f2bf(float f) {
    unsigned u = __float_as_uint(f);
    u += 0x7fff + ((u >> 16) & 1);
    return (unsigned short)(u >> 16);
}
static __device__ __forceinline__ float bf2f(unsigned short h) {
    return __uint_as_float((unsigned)h << 16);
}
static __device__ __forceinline__ unsigned packsplit(float f) {
    unsigned short hi = f2bf(f);
    unsigned short lo = f2bf(f - bf2f(hi));
    return ((unsigned)hi << 16) | lo;
}

// ---------------- CSR build (degi memset to 0 by host-side hipMemsetAsync) ----------------
// CSR contains ONLY the E real edges; self-loops are streamed in agg_kernel.

__global__ void count_kernel(const int* __restrict__ ei, int* degi, int E) {
    int e = blockIdx.x * 256 + threadIdx.x;
    if (e < E) atomicAdd(&degi[ei[E + e]], 1);   // col = dest
}

// per-block sums of 256 deg values (real edges only), + fused dinv (deg+1 incl self-loop)
__global__ __launch_bounds__(256) void scan_bsum_kernel(const int* __restrict__ degi,
                                                        float* __restrict__ dinv,
                                                        int* bsum, int n) {
    int tid = threadIdx.x;
    int i = blockIdx.x * 256 + tid;
    int d = (i < n) ? degi[i] : 0;
    if (i < n) dinv[i] = rsqrtf((float)(d + 1));  // +1 self-loop for normalization
    int v = d;                                    // offsets count only real edges
    #pragma unroll
    for (int off = 32; off > 0; off >>= 1) v += __shfl_down(v, off);
    __shared__ int ws[4];
    if ((tid & 63) == 0) ws[tid >> 6] = v;
    __syncthreads();
    if (tid == 0) bsum[blockIdx.x] = ws[0] + ws[1] + ws[2] + ws[3];
}

// emit rp/cursor; fused block-offset reduction
__global__ __launch_bounds__(256) void scan_emit_kernel(const int* __restrict__ degi,
                                                        const int* __restrict__ bsum,
                                                        int* rp, int* cursor, int n, int nb) {
    int tid = threadIdx.x;
    int bid = blockIdx.x;
    int contrib = 0;
    for (int t = tid; t < bid; t += 256) contrib += bsum[t];
    int cr = contrib;
    #pragma unroll
    for (int off = 32; off > 0; off >>= 1) cr += __shfl_down(cr, off);
    __shared__ int wr[4];
    __shared__ int s_boff;
    if ((tid & 63) == 0) wr[tid >> 6] = cr;
    __syncthreads();
    if (tid == 0) s_boff = wr[0] + wr[1] + wr[2] + wr[3];
    __syncthreads();

    int i = bid * 256 + tid;
    int v = (i < n) ? degi[i] : 0;                // real edges only
    int lane = tid & 63, wid = tid >> 6;
    int x = v;
    #pragma unroll
    for (int off = 1; off < 64; off <<= 1) {
        int y = __shfl_up(x, off);
        if (lane >= off) x += y;
    }
    __shared__ int ws[4];
    if (lane == 63) ws[wid] = x;
    __syncthreads();
    if (tid == 0) { int a = 0; for (int j = 0; j < 4; ++j) { int t = ws[j]; ws[j] = a; a += t; } }
    __syncthreads();
    int excl = x - v + ws[wid] + s_boff;
    if (i < n) { rp[i] = excl; cursor[i] = excl; }
    if (i == n - 1) rp[n] = excl + v;
}

__global__ void fill_kernel(const int* __restrict__ ei, const float* __restrict__ dinv,
                            int* cursor, long long* __restrict__ csr, int E) {
    int e = blockIdx.x * 256 + threadIdx.x;
    if (e >= E) return;
    int r = ei[e], c = ei[E + e];
    int pos = atomicAdd(&cursor[c], 1);
    float wv = dinv[r] * dinv[c];
    long long packed = (long long)(unsigned int)r
                     | ((long long)(unsigned int)__float_as_int(wv) << 32);
    csr[pos] = packed;
}

// ---------------- weight packing: W[k][n] -> Wt_hi[n][k], Wt_lo[n][k] ----------------

__global__ void packw_kernel(const float* w0, const float* w1, const float* w2,
                             const float* w3, const float* w4, const float* w5,
                             unsigned short* __restrict__ hi, unsigned short* __restrict__ lo) {
    int l = blockIdx.y;
    const float* W = (l == 0) ? w0 : (l == 1) ? w1 : (l == 2) ? w2
                   : (l == 3) ? w3 : (l == 4) ? w4 : w5;
    int idx = blockIdx.x * 256 + threadIdx.x;
    int k = idx >> 7, nn = idx & 127;
    float v = W[k * 128 + nn];
    unsigned short h = f2bf(v);
    unsigned short ls = f2bf(v - bf2f(h));
    hi[l * 16384 + nn * 128 + k] = h;
    lo[l * 16384 + nn * 128 + k] = ls;
}

// ---------------- split-bf16 MFMA GEMM core ----------------
// COLUMN-CHUNKED activation layout: M[c][node][16], c = 0..7 (chunk = col/16).
// Each chunk slice is a contiguous n*16*4 = 3.2 MB block -> fits one XCD's 4 MiB L2,
// enabling the XCD-pinned aggregation below.
// Wt staged into LDS (stride 260 shorts: hi[0..127], lo[128..255] per row).
// 512 threads = 8 waves x 16 rows = 128 rows/block.
// Fragments: a[j]=A[m=lane&15][k=quad*8+j], D: col=lane&15, row=quad*4+reg.

#define WLDS_STRIDE 260

static __device__ __forceinline__ void stage_w(const unsigned short* __restrict__ Wth,
                                               const unsigned short* __restrict__ Wtl,
                                               unsigned short* Wlds, int tid) {
    #pragma unroll
    for (int it = 0; it < 8; ++it) {
        int c = it * 512 + tid;
        int row = c >> 5, piece = c & 31;
        const unsigned short* src = (piece < 16)
            ? (Wth + (size_t)row * 128 + piece * 8)
            : (Wtl + (size_t)row * 128 + (piece - 16) * 8);
        int dst = row * WLDS_STRIDE + ((piece < 16) ? piece * 8 : 128 + (piece - 16) * 8);
        *(short8*)&Wlds[dst] = *(const short8*)src;
    }
}

static __device__ __forceinline__ void unpack_u(uint4 u0, uint4 u1, short8& ah, short8& al) {
    ah[0] = (short)(u0.x >> 16); al[0] = (short)(u0.x & 0xffff);
    ah[1] = (short)(u0.y >> 16); al[1] = (short)(u0.y & 0xffff);
    ah[2] = (short)(u0.z >> 16); al[2] = (short)(u0.z & 0xffff);
    ah[3] = (short)(u0.w >> 16); al[3] = (short)(u0.w & 0xffff);
    ah[4] = (short)(u1.x >> 16); al[4] = (short)(u1.x & 0xffff);
    ah[5] = (short)(u1.y >> 16); al[5] = (short)(u1.y & 0xffff);
    ah[6] = (short)(u1.z >> 16); al[6] = (short)(u1.z & 0xffff);
    ah[7] = (short)(u1.w >> 16); al[7] = (short)(u1.w & 0xffff);
}

// A read from chunked packed layout: element (row, k) at chunk = k>>4 = 2*kc + (quad>>1),
// offset (k&15) = (quad&1)*8 + idx.  u0/u1 stay within one chunk.
__global__ __launch_bounds__(512) void gemm_kernel(const unsigned* __restrict__ Ap,
                                                   const unsigned short* __restrict__ Wth,
                                                   const unsigned short* __restrict__ Wtl,
                                                   float* __restrict__ C, int n) {
    __shared__ unsigned short Wlds[128 * WLDS_STRIDE];
    int tid = threadIdx.x;
    int wave = tid >> 6, lane = tid & 63;
    int m = lane & 15, quad = lane >> 4;
    int row0 = blockIdx.x * 128 + wave * 16;
    int arow = row0 + m; if (arow > n - 1) arow = n - 1;
    size_t n16 = (size_t)n * 16;
    const unsigned* abase = Ap + (size_t)arow * 16 + (quad & 1) * 8;
    int chalf = quad >> 1;

    // prefetch kc=0 A before staging W (overlap global latency with LDS fill)
    uint4 p0 = *(const uint4*)(abase + (size_t)chalf * n16);
    uint4 p1 = *(const uint4*)(abase + (size_t)chalf * n16 + 4);

    stage_w(Wth, Wtl, Wlds, tid);

    floatx4 acc[8];
    #pragma unroll
    for (int ct = 0; ct < 8; ++ct) acc[ct] = (floatx4){0.f, 0.f, 0.f, 0.f};
    __syncthreads();

    #pragma unroll
    for (int kc = 0; kc < 4; ++kc) {
        uint4 u0, u1;
        if (kc == 0) { u0 = p0; u1 = p1; }
        else {
            const unsigned* ap = abase + (size_t)(2 * kc + chalf) * n16;
            u0 = *(const uint4*)(ap);
            u1 = *(const uint4*)(ap + 4);
        }
        short8 ah, al;
        unpack_u(u0, u1, ah, al);
        #pragma unroll
        for (int ct = 0; ct < 8; ++ct) {
            int base = (ct * 16 + m) * WLDS_STRIDE + kc * 32 + quad * 8;
            short8 wh = *(const short8*)&Wlds[base];
            short8 wl = *(const short8*)&Wlds[base + 128];
            acc[ct] = __builtin_amdgcn_mfma_f32_16x16x32_bf16(al, wl, acc[ct], 0, 0, 0);
            acc[ct] = __builtin_amdgcn_mfma_f32_16x16x32_bf16(ah, wl, acc[ct], 0, 0, 0);
            acc[ct] = __builtin_amdgcn_mfma_f32_16x16x32_bf16(al, wh, acc[ct], 0, 0, 0);
            acc[ct] = __builtin_amdgcn_mfma_f32_16x16x32_bf16(ah, wh, acc[ct], 0, 0, 0);
        }
    }
    // chunked C write: chunk index == ct
    #pragma unroll
    for (int ct = 0; ct < 8; ++ct) {
        #pragma unroll
        for (int r = 0; r < 4; ++r) {
            int row = row0 + quad * 4 + r;
            if (row < n) C[(size_t)ct * n16 + (size_t)row * 16 + m] = acc[ct][r];
        }
    }
}

// layer-0 variant: reads fp32 x (row-major input) directly, splits inline
__global__ __launch_bounds__(512) void gemm0_kernel(const float* __restrict__ X,
                                                    const unsigned short* __restrict__ Wth,
                                                    const unsigned short* __restrict__ Wtl,
                                                    float* __restrict__ C, int n) {
    __shared__ unsigned short Wlds[128 * WLDS_STRIDE];
    int tid = threadIdx.x;
    int wave = tid >> 6, lane = tid & 63;
    int m = lane & 15, quad = lane >> 4;
    int row0 = blockIdx.x * 128 + wave * 16;
    int arow = row0 + m; if (arow > n - 1) arow = n - 1;
    size_t n16 = (size_t)n * 16;
    const float* aptr = X + (size_t)arow * 128 + quad * 8;

    float4 pf0 = *(const float4*)(aptr);
    float4 pf1 = *(const float4*)(aptr + 4);

    stage_w(Wth, Wtl, Wlds, tid);

    floatx4 acc[8];
    #pragma unroll
    for (int ct = 0; ct < 8; ++ct) acc[ct] = (floatx4){0.f, 0.f, 0.f, 0.f};
    __syncthreads();

    #pragma unroll
    for (int kc = 0; kc < 4; ++kc) {
        float4 f0, f1;
        if (kc == 0) { f0 = pf0; f1 = pf1; }
        else { f0 = *(const float4*)(aptr + kc * 32); f1 = *(const float4*)(aptr + kc * 32 + 4); }
        float fv[8] = {f0.x, f0.y, f0.z, f0.w, f1.x, f1.y, f1.z, f1.w};
        short8 ah, al;
        #pragma unroll
        for (int j = 0; j < 8; ++j) {
            unsigned short h = f2bf(fv[j]);
            ah[j] = (short)h;
            al[j] = (short)f2bf(fv[j] - bf2f(h));
        }
        #pragma unroll
        for (int ct = 0; ct < 8; ++ct) {
            int base = (ct * 16 + m) * WLDS_STRIDE + kc * 32 + quad * 8;
            short8 wh = *(const short8*)&Wlds[base];
            short8 wl = *(const short8*)&Wlds[base + 128];
            acc[ct] = __builtin_amdgcn_mfma_f32_16x16x32_bf16(al, wl, acc[ct], 0, 0, 0);
            acc[ct] = __builtin_amdgcn_mfma_f32_16x16x32_bf16(ah, wl, acc[ct], 0, 0, 0);
            acc[ct] = __builtin_amdgcn_mfma_f32_16x16x32_bf16(al, wh, acc[ct], 0, 0, 0);
            acc[ct] = __builtin_amdgcn_mfma_f32_16x16x32_bf16(ah, wh, acc[ct], 0, 0, 0);
        }
    }
    #pragma unroll
    for (int ct = 0; ct < 8; ++ct) {
        #pragma unroll
        for (int r = 0; r < 4; ++r) {
            int row = row0 + quad * 4 + r;
            if (row < n) C[(size_t)ct * n16 + (size_t)row * 16 + m] = acc[ct][r];
        }
    }
}

// ---------------- aggregation: XCD-pinned column chunks ----------------
// chunk = blockIdx.x % 8 -> round-robin dispatch pins all blocks of a chunk to one XCD;
// that XCD's gathers touch only its 3.2 MB contiguous slice of t -> L2-resident.
// One node per 4-lane group (each lane: 4 of the chunk's 16 cols, 64 B gather/edge).
// Masked unroll-8 keeps 8 csr loads + 8 gathers in flight.

__global__ __launch_bounds__(256) void agg_kernel(const float* __restrict__ t,
                                                  const float* __restrict__ bias,
                                                  const int* __restrict__ rp,
                                                  const long long* __restrict__ csr,
                                                  const float* __restrict__ dinv,
                                                  unsigned* __restrict__ hp, int n) {
    int chunk = blockIdx.x & 7;
    int nb = blockIdx.x >> 3;
    int group = threadIdx.x >> 2;
    int lane4 = threadIdx.x & 3;
    int j = nb * 64 + group;
    if (j >= n) return;
    size_t n16 = (size_t)n * 16;
    const float* tc = t + (size_t)chunk * n16;
    int c4 = lane4 * 4;
    int p0 = rp[j], p1 = rp[j + 1];

    // self-loop term: coalesced sequential read, issued first
    float dj = dinv[j];
    float ws = dj * dj;
    float4 vs = *(const float4*)&tc[(size_t)j * 16 + c4];

    float4 acc[4];
    acc[0] = make_float4(ws * vs.x, ws * vs.y, ws * vs.z, ws * vs.w);
    acc[1] = make_float4(0.f, 0.f, 0.f, 0.f);
    acc[2] = make_float4(0.f, 0.f, 0.f, 0.f);
    acc[3] = make_float4(0.f, 0.f, 0.f, 0.f);

    for (int p = p0; p < p1; p += 8) {
        int lim = p1 - 1;
        long long e[8];
        #pragma unroll
        for (int i = 0; i < 8; ++i) e[i] = csr[min(p + i, lim)];
        float w[8];
        #pragma unroll
        for (int i = 0; i < 8; ++i)
            w[i] = (p + i < p1) ? __int_as_float((int)(e[i] >> 32)) : 0.f;
        float4 v[8];
        #pragma unroll
        for (int i = 0; i < 8; ++i)
            v[i] = *(const float4*)&tc[(size_t)(int)e[i] * 16 + c4];
        #pragma unroll
        for (int i = 0; i < 8; ++i) {
            acc[i & 3].x += w[i] * v[i].x;
            acc[i & 3].y += w[i] * v[i].y;
            acc[i & 3].z += w[i] * v[i].z;
            acc[i & 3].w += w[i] * v[i].w;
        }
    }

    float4 b = *(const float4*)&bias[chunk * 16 + c4];
    float ox = fmaxf(acc[0].x + acc[1].x + acc[2].x + acc[3].x + b.x, 0.f);
    float oy = fmaxf(acc[0].y + acc[1].y + acc[2].y + acc[3].y + b.y, 0.f);
    float oz = fmaxf(acc[0].z + acc[1].z + acc[2].z + acc[3].z + b.z, 0.f);
    float ow = fmaxf(acc[0].w + acc[1].w + acc[2].w + acc[3].w + b.w, 0.f);
    uint4 st;
    st.x = packsplit(ox); st.y = packsplit(oy); st.z = packsplit(oz); st.w = packsplit(ow);
    *(uint4*)&hp[(size_t)chunk * n16 + (size_t)j * 16 + c4] = st;
}

// ---------------- pooling + classifier (one block per graph, no atomics) ----------------

__global__ __launch_bounds__(256) void pool_kernel(const float* __restrict__ t,
                                                   const float* __restrict__ bfc,
                                                   const int* __restrict__ batch,
                                                   const float* __restrict__ Wlin,
                                                   const float* __restrict__ blin,
                                                   float* __restrict__ out, int n) {
    int g = blockIdx.x;
    int tid = threadIdx.x;
    int lo = 0, hi = n;
    while (lo < hi) { int m = (lo + hi) >> 1; if (batch[m] < g) lo = m + 1; else hi = m; }
    int start = lo;
    lo = start; hi = n;
    while (lo < hi) { int m = (lo + hi) >> 1; if (batch[m] < g + 1) lo = m + 1; else hi = m; }
    int end = lo;

    size_t n16 = (size_t)n * 16;
    int lane = tid & 31, sub = tid >> 5;
    int c4 = lane * 4;
    const float* tc = t + (size_t)(c4 >> 4) * n16;   // chunk = c4/16
    int co = c4 & 15;
    float4 bv = *(const float4*)&bfc[c4];
    float sx = 0.f, sy = 0.f, sz = 0.f, sw = 0.f;
    for (int j = start + sub; j < end; j += 8) {
        float4 v = *(const float4*)&tc[(size_t)j * 16 + co];
        sx += fmaxf(v.x + bv.x, 0.f);
        sy += fmaxf(v.y + bv.y, 0.f);
        sz += fmaxf(v.z + bv.z, 0.f);
        sw += fmaxf(v.w + bv.w, 0.f);
    }
    __shared__ float red[8][128];
    red[sub][c4] = sx; red[sub][c4 + 1] = sy; red[sub][c4 + 2] = sz; red[sub][c4 + 3] = sw;
    __syncthreads();
    __shared__ float pooled[128];
    if (tid < 128) {
        float s = 0.f;
        #pragma unroll
        for (int k = 0; k < 8; ++k) s += red[k][tid];
        float pv = s / fmaxf((float)(end - start), 1.f);
        pooled[tid] = pv;
        out[1280 + g * 128 + tid] = pv;
    }
    __syncthreads();
    if (tid < 10) {
        float a = blin[tid];
        for (int k = 0; k < 128; ++k) a += pooled[k] * Wlin[k * 10 + tid];
        out[g * 10 + tid] = a;
    }
}

// ---------------- launch ----------------

extern "C" void kernel_launch(void* const* d_in, const int* in_sizes, int n_in,
                              void* d_out, int out_size, void* d_ws, size_t ws_size,
                              hipStream_t stream) {
    const float* x     = (const float*)d_in[0];
    const int*   ei    = (const int*)d_in[1];
    const int*   batch = (const int*)d_in[2];
    const float* Wl[6] = {(const float*)d_in[3], (const float*)d_in[5], (const float*)d_in[7],
                          (const float*)d_in[9], (const float*)d_in[11], (const float*)d_in[13]};
    const float* bl[6] = {(const float*)d_in[4], (const float*)d_in[6], (const float*)d_in[8],
                          (const float*)d_in[10], (const float*)d_in[12], (const float*)d_in[14]};
    const float* Wlin = (const float*)d_in[15];
    const float* blin = (const float*)d_in[16];

    const int N = in_sizes[2];        // 50000
    const int E = in_sizes[1] / 2;    // 600000
    (void)n_in; (void)out_size; (void)ws_size;

    char* p = (char*)d_ws;
    auto carve = [&](size_t bytes) { void* r = (void*)p; p += (bytes + 255) & ~(size_t)255; return r; };
    float*          t      = (float*)carve((size_t)N * 128 * 4);      // fp32 gemm output (chunked)
    unsigned*       hp     = (unsigned*)carve((size_t)N * 128 * 4);   // packed agg output (chunked)
    int*            degi   = (int*)carve((size_t)N * 4);
    float*          dinv   = (float*)carve((size_t)N * 4);
    int*            rp     = (int*)carve((size_t)(N + 1) * 4);
    int*            cursor = (int*)carve((size_t)N * 4);
    long long*      csr    = (long long*)carve((size_t)(E + N) * 8);
    int*            bsum   = (int*)carve(256 * 4);
    unsigned short* wth    = (unsigned short*)carve(6 * 16384 * 2);
    unsigned short* wtl    = (unsigned short*)carve(6 * 16384 * 2);

    int gN = (N + 255) / 256;
    hipMemsetAsync(degi, 0, (size_t)N * 4, stream);
    count_kernel<<<(E + 255) / 256, 256, 0, stream>>>(ei, degi, E);
    scan_bsum_kernel<<<gN, 256, 0, stream>>>(degi, dinv, bsum, N);
    scan_emit_kernel<<<gN, 256, 0, stream>>>(degi, bsum, rp, cursor, N, gN);
    fill_kernel<<<(E + 255) / 256, 256, 0, stream>>>(ei, dinv, cursor, csr, E);
    packw_kernel<<<dim3(64, 6), 256, 0, stream>>>(Wl[0], Wl[1], Wl[2], Wl[3], Wl[4], Wl[5],
                                                  wth, wtl);

    int gGemm = (N + 127) / 128;
    int gAgg  = 8 * ((N + 63) / 64);   // chunk = blockIdx % 8 -> XCD pinning
    gemm0_kernel<<<gGemm, 512, 0, stream>>>(x, wth, wtl, t, N);
    agg_kernel<<<gAgg, 256, 0, stream>>>(t, bl[0], rp, csr, dinv, hp, N);
    for (int l = 1; l < 5; ++l) {
        gemm_kernel<<<gGemm, 512, 0, stream>>>(hp, wth + l * 16384, wtl + l * 16384, t, N);
        agg_kernel<<<gAgg, 256, 0, stream>>>(t, bl[l], rp, csr, dinv, hp, N);
    }
    gemm_kernel<<<gGemm, 512, 0, stream>>>(hp, wth + 5 * 16384, wtl + 5 * 16384, t, N);
    pool_kernel<<<128, 256, 0, stream>>>(t, bl[5], batch, Wlin, blin, (float*)d_out, N);
}

// Round 3
// 409.420 us; speedup vs baseline: 1.2380x; 1.2056x over previous
//
#include <hip/hip_runtime.h>

typedef __attribute__((ext_vector_type(8))) short short8;
typedef __attribute__((ext_vector_type(4))) float floatx4;
typedef __attribute__((ext_vector_type(8))) _Float16 half8;

// ---- bf16 split helpers (round-to-nearest-even) ----
static __device__ __forceinline__ unsigned short f2bf(float f) {
    unsigned u = __float_as_uint(f);
    u += 0x7fff + ((u >> 16) & 1);
    return (unsigned short)(u >> 16);
}
static __device__ __forceinline__ float bf2f(unsigned short h) {
    return __uint_as_float((unsigned)h << 16);
}
static __device__ __forceinline__ unsigned packsplit(float f) {
    unsigned short hi = f2bf(f);
    unsigned short lo = f2bf(f - bf2f(hi));
    return ((unsigned)hi << 16) | lo;
}

// ---------------- CSR build (degi memset to 0 by host-side hipMemsetAsync) ----------------
// CSR contains ONLY the E real edges; self-loops are streamed in agg_kernel.

__global__ void count_kernel(const int* __restrict__ ei, int* degi, int E) {
    int e = blockIdx.x * 256 + threadIdx.x;
    if (e < E) atomicAdd(&degi[ei[E + e]], 1);   // col = dest
}

__global__ __launch_bounds__(256) void scan_bsum_kernel(const int* __restrict__ degi,
                                                        float* __restrict__ dinv,
                                                        int* bsum, int n) {
    int tid = threadIdx.x;
    int i = blockIdx.x * 256 + tid;
    int d = (i < n) ? degi[i] : 0;
    if (i < n) dinv[i] = rsqrtf((float)(d + 1));  // +1 self-loop for normalization
    int v = d;                                    // offsets count only real edges
    #pragma unroll
    for (int off = 32; off > 0; off >>= 1) v += __shfl_down(v, off);
    __shared__ int ws[4];
    if ((tid & 63) == 0) ws[tid >> 6] = v;
    __syncthreads();
    if (tid == 0) bsum[blockIdx.x] = ws[0] + ws[1] + ws[2] + ws[3];
}

__global__ __launch_bounds__(256) void scan_emit_kernel(const int* __restrict__ degi,
                                                        const int* __restrict__ bsum,
                                                        int* rp, int* cursor, int n, int nb) {
    int tid = threadIdx.x;
    int bid = blockIdx.x;
    int contrib = 0;
    for (int t = tid; t < bid; t += 256) contrib += bsum[t];
    int cr = contrib;
    #pragma unroll
    for (int off = 32; off > 0; off >>= 1) cr += __shfl_down(cr, off);
    __shared__ int wr[4];
    __shared__ int s_boff;
    if ((tid & 63) == 0) wr[tid >> 6] = cr;
    __syncthreads();
    if (tid == 0) s_boff = wr[0] + wr[1] + wr[2] + wr[3];
    __syncthreads();

    int i = bid * 256 + tid;
    int v = (i < n) ? degi[i] : 0;
    int lane = tid & 63, wid = tid >> 6;
    int x = v;
    #pragma unroll
    for (int off = 1; off < 64; off <<= 1) {
        int y = __shfl_up(x, off);
        if (lane >= off) x += y;
    }
    __shared__ int ws[4];
    if (lane == 63) ws[wid] = x;
    __syncthreads();
    if (tid == 0) { int a = 0; for (int j = 0; j < 4; ++j) { int t = ws[j]; ws[j] = a; a += t; } }
    __syncthreads();
    int excl = x - v + ws[wid] + s_boff;
    if (i < n) { rp[i] = excl; cursor[i] = excl; }
    if (i == n - 1) rp[n] = excl + v;
}

__global__ void fill_kernel(const int* __restrict__ ei, const float* __restrict__ dinv,
                            int* cursor, long long* __restrict__ csr, int E) {
    int e = blockIdx.x * 256 + threadIdx.x;
    if (e >= E) return;
    int r = ei[e], c = ei[E + e];
    int pos = atomicAdd(&cursor[c], 1);
    float wv = dinv[r] * dinv[c];
    long long packed = (long long)(unsigned int)r
                     | ((long long)(unsigned int)__float_as_int(wv) << 32);
    csr[pos] = packed;
}

// ---------------- weight packing: W[k][n] -> Wt_hi[n][k], Wt_lo[n][k] ----------------

__global__ void packw_kernel(const float* w0, const float* w1, const float* w2,
                             const float* w3, const float* w4, const float* w5,
                             unsigned short* __restrict__ hi, unsigned short* __restrict__ lo) {
    int l = blockIdx.y;
    const float* W = (l == 0) ? w0 : (l == 1) ? w1 : (l == 2) ? w2
                   : (l == 3) ? w3 : (l == 4) ? w4 : w5;
    int idx = blockIdx.x * 256 + threadIdx.x;
    int k = idx >> 7, nn = idx & 127;
    float v = W[k * 128 + nn];
    unsigned short h = f2bf(v);
    unsigned short ls = f2bf(v - bf2f(h));
    hi[l * 16384 + nn * 128 + k] = h;
    lo[l * 16384 + nn * 128 + k] = ls;
}

// ---------------- split-bf16 MFMA GEMM core ----------------
// A-input: hp packed split-bf16, chunked [8][node][16] (chunk = col/16) — unchanged.
// Output modes: outf=0 -> _Float16 chunked [4][node][32] (gather operand for agg);
//               outf=1 -> fp32 row-major [node][128]   (final layer, feeds pool).
// Wt staged into LDS (stride 260 shorts: hi[0..127], lo[128..255] per row).
// 512 threads = 8 waves x 16 rows = 128 rows/block.
// Fragments: a[j]=A[m=lane&15][k=quad*8+j], D: col=lane&15, row=quad*4+reg.

#define WLDS_STRIDE 260

static __device__ __forceinline__ void stage_w(const unsigned short* __restrict__ Wth,
                                               const unsigned short* __restrict__ Wtl,
                                               unsigned short* Wlds, int tid) {
    #pragma unroll
    for (int it = 0; it < 8; ++it) {
        int c = it * 512 + tid;
        int row = c >> 5, piece = c & 31;
        const unsigned short* src = (piece < 16)
            ? (Wth + (size_t)row * 128 + piece * 8)
            : (Wtl + (size_t)row * 128 + (piece - 16) * 8);
        int dst = row * WLDS_STRIDE + ((piece < 16) ? piece * 8 : 128 + (piece - 16) * 8);
        *(short8*)&Wlds[dst] = *(const short8*)src;
    }
}

static __device__ __forceinline__ void unpack_u(uint4 u0, uint4 u1, short8& ah, short8& al) {
    ah[0] = (short)(u0.x >> 16); al[0] = (short)(u0.x & 0xffff);
    ah[1] = (short)(u0.y >> 16); al[1] = (short)(u0.y & 0xffff);
    ah[2] = (short)(u0.z >> 16); al[2] = (short)(u0.z & 0xffff);
    ah[3] = (short)(u0.w >> 16); al[3] = (short)(u0.w & 0xffff);
    ah[4] = (short)(u1.x >> 16); al[4] = (short)(u1.x & 0xffff);
    ah[5] = (short)(u1.y >> 16); al[5] = (short)(u1.y & 0xffff);
    ah[6] = (short)(u1.z >> 16); al[6] = (short)(u1.z & 0xffff);
    ah[7] = (short)(u1.w >> 16); al[7] = (short)(u1.w & 0xffff);
}

static __device__ __forceinline__ void gemm_store(float C_acc, void* __restrict__ C,
                                                  int outf, int ct, int row, int m, size_t n32) {
    if (outf) {
        ((float*)C)[(size_t)row * 128 + ct * 16 + m] = C_acc;
    } else {
        _Float16* th = (_Float16*)C;
        th[(size_t)(ct >> 1) * n32 + (size_t)row * 32 + (ct & 1) * 16 + m] = (_Float16)C_acc;
    }
}

__global__ __launch_bounds__(512) void gemm_kernel(const unsigned* __restrict__ Ap,
                                                   const unsigned short* __restrict__ Wth,
                                                   const unsigned short* __restrict__ Wtl,
                                                   void* __restrict__ C, int n, int outf) {
    __shared__ unsigned short Wlds[128 * WLDS_STRIDE];
    int tid = threadIdx.x;
    int wave = tid >> 6, lane = tid & 63;
    int m = lane & 15, quad = lane >> 4;
    int row0 = blockIdx.x * 128 + wave * 16;
    int arow = row0 + m; if (arow > n - 1) arow = n - 1;
    size_t n16 = (size_t)n * 16;
    size_t n32 = (size_t)n * 32;
    const unsigned* abase = Ap + (size_t)arow * 16 + (quad & 1) * 8;
    int chalf = quad >> 1;

    uint4 p0 = *(const uint4*)(abase + (size_t)chalf * n16);
    uint4 p1 = *(const uint4*)(abase + (size_t)chalf * n16 + 4);

    stage_w(Wth, Wtl, Wlds, tid);

    floatx4 acc[8];
    #pragma unroll
    for (int ct = 0; ct < 8; ++ct) acc[ct] = (floatx4){0.f, 0.f, 0.f, 0.f};
    __syncthreads();

    #pragma unroll
    for (int kc = 0; kc < 4; ++kc) {
        uint4 u0, u1;
        if (kc == 0) { u0 = p0; u1 = p1; }
        else {
            const unsigned* ap = abase + (size_t)(2 * kc + chalf) * n16;
            u0 = *(const uint4*)(ap);
            u1 = *(const uint4*)(ap + 4);
        }
        short8 ah, al;
        unpack_u(u0, u1, ah, al);
        #pragma unroll
        for (int ct = 0; ct < 8; ++ct) {
            int base = (ct * 16 + m) * WLDS_STRIDE + kc * 32 + quad * 8;
            short8 wh = *(const short8*)&Wlds[base];
            short8 wl = *(const short8*)&Wlds[base + 128];
            acc[ct] = __builtin_amdgcn_mfma_f32_16x16x32_bf16(al, wl, acc[ct], 0, 0, 0);
            acc[ct] = __builtin_amdgcn_mfma_f32_16x16x32_bf16(ah, wl, acc[ct], 0, 0, 0);
            acc[ct] = __builtin_amdgcn_mfma_f32_16x16x32_bf16(al, wh, acc[ct], 0, 0, 0);
            acc[ct] = __builtin_amdgcn_mfma_f32_16x16x32_bf16(ah, wh, acc[ct], 0, 0, 0);
        }
    }
    #pragma unroll
    for (int ct = 0; ct < 8; ++ct) {
        #pragma unroll
        for (int r = 0; r < 4; ++r) {
            int row = row0 + quad * 4 + r;
            if (row < n) gemm_store(acc[ct][r], C, outf, ct, row, m, n32);
        }
    }
}

// layer-0 variant: reads fp32 x (row-major input) directly; always fp16-chunked out
__global__ __launch_bounds__(512) void gemm0_kernel(const float* __restrict__ X,
                                                    const unsigned short* __restrict__ Wth,
                                                    const unsigned short* __restrict__ Wtl,
                                                    _Float16* __restrict__ C, int n) {
    __shared__ unsigned short Wlds[128 * WLDS_STRIDE];
    int tid = threadIdx.x;
    int wave = tid >> 6, lane = tid & 63;
    int m = lane & 15, quad = lane >> 4;
    int row0 = blockIdx.x * 128 + wave * 16;
    int arow = row0 + m; if (arow > n - 1) arow = n - 1;
    size_t n32 = (size_t)n * 32;
    const float* aptr = X + (size_t)arow * 128 + quad * 8;

    float4 pf0 = *(const float4*)(aptr);
    float4 pf1 = *(const float4*)(aptr + 4);

    stage_w(Wth, Wtl, Wlds, tid);

    floatx4 acc[8];
    #pragma unroll
    for (int ct = 0; ct < 8; ++ct) acc[ct] = (floatx4){0.f, 0.f, 0.f, 0.f};
    __syncthreads();

    #pragma unroll
    for (int kc = 0; kc < 4; ++kc) {
        float4 f0, f1;
        if (kc == 0) { f0 = pf0; f1 = pf1; }
        else { f0 = *(const float4*)(aptr + kc * 32); f1 = *(const float4*)(aptr + kc * 32 + 4); }
        float fv[8] = {f0.x, f0.y, f0.z, f0.w, f1.x, f1.y, f1.z, f1.w};
        short8 ah, al;
        #pragma unroll
        for (int j = 0; j < 8; ++j) {
            unsigned short h = f2bf(fv[j]);
            ah[j] = (short)h;
            al[j] = (short)f2bf(fv[j] - bf2f(h));
        }
        #pragma unroll
        for (int ct = 0; ct < 8; ++ct) {
            int base = (ct * 16 + m) * WLDS_STRIDE + kc * 32 + quad * 8;
            short8 wh = *(const short8*)&Wlds[base];
            short8 wl = *(const short8*)&Wlds[base + 128];
            acc[ct] = __builtin_amdgcn_mfma_f32_16x16x32_bf16(al, wl, acc[ct], 0, 0, 0);
            acc[ct] = __builtin_amdgcn_mfma_f32_16x16x32_bf16(ah, wl, acc[ct], 0, 0, 0);
            acc[ct] = __builtin_amdgcn_mfma_f32_16x16x32_bf16(al, wh, acc[ct], 0, 0, 0);
            acc[ct] = __builtin_amdgcn_mfma_f32_16x16x32_bf16(ah, wh, acc[ct], 0, 0, 0);
        }
    }
    #pragma unroll
    for (int ct = 0; ct < 8; ++ct) {
        #pragma unroll
        for (int r = 0; r < 4; ++r) {
            int row = row0 + quad * 4 + r;
            if (row < n)
                C[(size_t)(ct >> 1) * n32 + (size_t)row * 32 + (ct & 1) * 16 + m] =
                    (_Float16)acc[ct][r];
        }
    }
}

// ---------------- aggregation: fp16 gather, 4 chunks of 32 cols, XCD-pinned ----------------
// t layout: [4][node][32] fp16 -> one node-chunk = 64 B = exactly ONE cache line.
// 4 lines/edge total (was 8 with fp32): halves the scattered-transaction count.
// blockIdx%8 = s: chunk = s&3, node-half = s>>2  -> chunk c served by XCDs {c, c+4},
// each caching the full 3.2 MB slice in its 4 MiB L2.
// One node per 4-lane group (lane: 8 fp16 cols = 16 B). Masked unroll-8.
// Aggregation math fp32; output hp = exact packed split-bf16 [8][node][16] (unchanged).

__global__ __launch_bounds__(256) void agg_kernel(const _Float16* __restrict__ t,
                                                  const float* __restrict__ bias,
                                                  const int* __restrict__ rp,
                                                  const long long* __restrict__ csr,
                                                  const float* __restrict__ dinv,
                                                  unsigned* __restrict__ hp, int n, int nh) {
    int s = blockIdx.x & 7;
    int chunk = s & 3;
    int half = s >> 2;
    int nb = blockIdx.x >> 3;
    int group = threadIdx.x >> 2;          // 64 nodes per block
    int lane4 = threadIdx.x & 3;
    int j = half * nh + nb * 64 + group;
    int jend = half ? n : nh;
    if (j >= jend) return;
    size_t n32 = (size_t)n * 32;
    const _Float16* tc = t + (size_t)chunk * n32;
    int c8 = lane4 * 8;                    // col offset within the 32-col chunk
    int p0 = rp[j], p1 = rp[j + 1];

    // self-loop: coalesced sequential read, issued first
    float dj = dinv[j];
    float wsf = dj * dj;
    half8 vs = *(const half8*)&tc[(size_t)j * 32 + c8];

    float acc[8];
    #pragma unroll
    for (int k = 0; k < 8; ++k) acc[k] = wsf * (float)vs[k];

    for (int p = p0; p < p1; p += 8) {
        int lim = p1 - 1;
        long long e[8];
        #pragma unroll
        for (int i = 0; i < 8; ++i) e[i] = csr[min(p + i, lim)];
        float w[8];
        #pragma unroll
        for (int i = 0; i < 8; ++i)
            w[i] = (p + i < p1) ? __int_as_float((int)(e[i] >> 32)) : 0.f;
        half8 v[8];
        #pragma unroll
        for (int i = 0; i < 8; ++i)
            v[i] = *(const half8*)&tc[(size_t)(int)e[i] * 32 + c8];
        #pragma unroll
        for (int i = 0; i < 8; ++i) {
            #pragma unroll
            for (int k = 0; k < 8; ++k) acc[k] += w[i] * (float)v[i][k];
        }
    }

    int cbase = chunk * 32 + c8;
    float4 b0 = *(const float4*)&bias[cbase];
    float4 b1 = *(const float4*)&bias[cbase + 4];
    float bb[8] = {b0.x, b0.y, b0.z, b0.w, b1.x, b1.y, b1.z, b1.w};
    unsigned st[8];
    #pragma unroll
    for (int k = 0; k < 8; ++k) st[k] = packsplit(fmaxf(acc[k] + bb[k], 0.f));

    size_t n16 = (size_t)n * 16;
    int hc = chunk * 2 + (lane4 >> 1);
    unsigned* dst = &hp[(size_t)hc * n16 + (size_t)j * 16 + (lane4 & 1) * 8];
    *(uint4*)dst = make_uint4(st[0], st[1], st[2], st[3]);
    *(uint4*)(dst + 4) = make_uint4(st[4], st[5], st[6], st[7]);
}

// ---------------- pooling + classifier (row-major fp32 final activations) ----------------

__global__ __launch_bounds__(256) void pool_kernel(const float* __restrict__ t,
                                                   const float* __restrict__ bfc,
                                                   const int* __restrict__ batch,
                                                   const float* __restrict__ Wlin,
                                                   const float* __restrict__ blin,
                                                   float* __restrict__ out, int n) {
    int g = blockIdx.x;
    int tid = threadIdx.x;
    int lo = 0, hi = n;
    while (lo < hi) { int m = (lo + hi) >> 1; if (batch[m] < g) lo = m + 1; else hi = m; }
    int start = lo;
    lo = start; hi = n;
    while (lo < hi) { int m = (lo + hi) >> 1; if (batch[m] < g + 1) lo = m + 1; else hi = m; }
    int end = lo;

    int lane = tid & 31, sub = tid >> 5;
    int c4 = lane * 4;
    float4 bv = *(const float4*)&bfc[c4];
    float sx = 0.f, sy = 0.f, sz = 0.f, sw = 0.f;
    for (int j = start + sub; j < end; j += 8) {
        float4 v = *(const float4*)&t[(size_t)j * 128 + c4];
        sx += fmaxf(v.x + bv.x, 0.f);
        sy += fmaxf(v.y + bv.y, 0.f);
        sz += fmaxf(v.z + bv.z, 0.f);
        sw += fmaxf(v.w + bv.w, 0.f);
    }
    __shared__ float red[8][128];
    red[sub][c4] = sx; red[sub][c4 + 1] = sy; red[sub][c4 + 2] = sz; red[sub][c4 + 3] = sw;
    __syncthreads();
    __shared__ float pooled[128];
    if (tid < 128) {
        float s = 0.f;
        #pragma unroll
        for (int k = 0; k < 8; ++k) s += red[k][tid];
        float pv = s / fmaxf((float)(end - start), 1.f);
        pooled[tid] = pv;
        out[1280 + g * 128 + tid] = pv;
    }
    __syncthreads();
    if (tid < 10) {
        float a = blin[tid];
        for (int k = 0; k < 128; ++k) a += pooled[k] * Wlin[k * 10 + tid];
        out[g * 10 + tid] = a;
    }
}

// ---------------- launch ----------------

extern "C" void kernel_launch(void* const* d_in, const int* in_sizes, int n_in,
                              void* d_out, int out_size, void* d_ws, size_t ws_size,
                              hipStream_t stream) {
    const float* x     = (const float*)d_in[0];
    const int*   ei    = (const int*)d_in[1];
    const int*   batch = (const int*)d_in[2];
    const float* Wl[6] = {(const float*)d_in[3], (const float*)d_in[5], (const float*)d_in[7],
                          (const float*)d_in[9], (const float*)d_in[11], (const float*)d_in[13]};
    const float* bl[6] = {(const float*)d_in[4], (const float*)d_in[6], (const float*)d_in[8],
                          (const float*)d_in[10], (const float*)d_in[12], (const float*)d_in[14]};
    const float* Wlin = (const float*)d_in[15];
    const float* blin = (const float*)d_in[16];

    const int N = in_sizes[2];        // 50000
    const int E = in_sizes[1] / 2;    // 600000
    (void)n_in; (void)out_size; (void)ws_size;

    char* p = (char*)d_ws;
    auto carve = [&](size_t bytes) { void* r = (void*)p; p += (bytes + 255) & ~(size_t)255; return r; };
    // th (fp16 gather operand, layers 0-4) and tf (fp32 final activations) share a region:
    // th is dead before the final gemm writes tf (gemm5 reads hp only).
    void*           treg   = carve((size_t)N * 128 * 4);              // max(N*128*2, N*128*4)
    _Float16*       th     = (_Float16*)treg;
    float*          tf     = (float*)treg;
    unsigned*       hp     = (unsigned*)carve((size_t)N * 128 * 4);   // packed agg output (chunk8)
    int*            degi   = (int*)carve((size_t)N * 4);
    float*          dinv   = (float*)carve((size_t)N * 4);
    int*            rp     = (int*)carve((size_t)(N + 1) * 4);
    int*            cursor = (int*)carve((size_t)N * 4);
    long long*      csr    = (long long*)carve((size_t)(E + N) * 8);
    int*            bsum   = (int*)carve(256 * 4);
    unsigned short* wth    = (unsigned short*)carve(6 * 16384 * 2);
    unsigned short* wtl    = (unsigned short*)carve(6 * 16384 * 2);

    int gN = (N + 255) / 256;
    hipMemsetAsync(degi, 0, (size_t)N * 4, stream);
    count_kernel<<<(E + 255) / 256, 256, 0, stream>>>(ei, degi, E);
    scan_bsum_kernel<<<gN, 256, 0, stream>>>(degi, dinv, bsum, N);
    scan_emit_kernel<<<gN, 256, 0, stream>>>(degi, bsum, rp, cursor, N, gN);
    fill_kernel<<<(E + 255) / 256, 256, 0, stream>>>(ei, dinv, cursor, csr, E);
    packw_kernel<<<dim3(64, 6), 256, 0, stream>>>(Wl[0], Wl[1], Wl[2], Wl[3], Wl[4], Wl[5],
                                                  wth, wtl);

    int NH = (N + 1) / 2;
    int gGemm = (N + 127) / 128;
    int gAgg  = 8 * ((NH + 63) / 64);   // s = bid%8: chunk = s&3, node-half = s>>2
    gemm0_kernel<<<gGemm, 512, 0, stream>>>(x, wth, wtl, th, N);
    agg_kernel<<<gAgg, 256, 0, stream>>>(th, bl[0], rp, csr, dinv, hp, N, NH);
    for (int l = 1; l < 5; ++l) {
        gemm_kernel<<<gGemm, 512, 0, stream>>>(hp, wth + l * 16384, wtl + l * 16384,
                                               (void*)th, N, 0);
        agg_kernel<<<gAgg, 256, 0, stream>>>(th, bl[l], rp, csr, dinv, hp, N, NH);
    }
    gemm_kernel<<<gGemm, 512, 0, stream>>>(hp, wth + 5 * 16384, wtl + 5 * 16384,
                                           (void*)tf, N, 1);
    pool_kernel<<<128, 256, 0, stream>>>(tf, bl[5], batch, Wlin, blin, (float*)d_out, N);
}